// Round 8
// baseline (208.196 us; speedup 1.0000x reference)
//
#include <hip/hip_runtime.h>
#include <math.h>

#define N_USERS 50000
#define N_ITEMS 50000
#define N_NODES 100000
#define HID     128
#define N_EDGES 1600000

// dst-bucket partition parameters
#define BKTW 512                  // nodes per dst-bucket
#define NBKT 196                  // ceil(N_NODES / BKTW)
#define NCOL 256                  // pass-A / hist blocks
#define EPB  (N_EDGES / NCOL)     // 6250 edges per block
#define NH   (NBKT * NCOL)        // 50176 (bucket, block) counts
#define SCAN_H 196                // NH/256
#define GEMV_BLKS (N_NODES / 16)  // 6250

// ---------------- weight collapse: the whole net is linear ----------------
// y = invd*sum_nbr(z_l) + z_r ; z_l = invd*sum_nbr(p_l)+q_l+c_l ; z_r likewise(+c)
// p_* = x0 . u_* ; q_* = x0 . v_* ; u/v = W1 @ (W2 @ Wout)
__global__ void k_prep(const float* __restrict__ Wl1, const float* __restrict__ Wr1,
                       const float* __restrict__ b1,  const float* __restrict__ Wl2,
                       const float* __restrict__ Wr2, const float* __restrict__ b2,
                       const float* __restrict__ Wout, const float* __restrict__ bout,
                       float* __restrict__ cvec, float* __restrict__ redsum) {
    __shared__ float w2l[HID], w2r[HID];
    int t = threadIdx.x;
    if (t < 128) {
        float s = 0.f;
        for (int j = 0; j < HID; ++j) s += Wl2[t * HID + j] * Wout[j];
        w2l[t] = s;
    } else {
        int k = t - 128;
        float s = 0.f;
        for (int j = 0; j < HID; ++j) s += Wr2[k * HID + j] * Wout[j];
        w2r[k] = s;
    }
    __syncthreads();
    if (t < 128) {
        float sl = 0.f, sr = 0.f;
        for (int j = 0; j < HID; ++j) {
            float w = Wl1[t * HID + j];
            sl += w * w2l[j];
            sr += w * w2r[j];
        }
        cvec[t]       = sl;  // u_l
        cvec[256 + t] = sr;  // u_r
    } else {
        int k = t - 128;
        float sl = 0.f, sr = 0.f;
        for (int j = 0; j < HID; ++j) {
            float w = Wr1[k * HID + j];
            sl += w * w2l[j];
            sr += w * w2r[j];
        }
        cvec[128 + k] = sl;  // v_l
        cvec[384 + k] = sr;  // v_r
    }
    if (t == 0) {
        float cl = 0.f;
        for (int j = 0; j < HID; ++j) cl += b1[j] * w2l[j];
        cvec[512] = cl;                       // c_l (folded into q_l)
    }
    if (t == 1) {
        float cr = 0.f, c = 0.f;
        for (int j = 0; j < HID; ++j) { cr += b1[j] * w2r[j]; c += b2[j] * Wout[j]; }
        cvec[513] = cr + c + bout[0];         // c_r + c_total (folded into q_r)
    }
    if (t == 2) *redsum = 0.f;
}

// ---------------- fused: 4-way GEMV (blocks < GEMV_BLKS) | bucket hist (rest) ----------------
__global__ __launch_bounds__(256) void k_gemvhist(const float* __restrict__ ue,
                                                  const float* __restrict__ ie,
                                                  const float* __restrict__ cvec,
                                                  float2* __restrict__ pq,
                                                  float2* __restrict__ qq,
                                                  const int* __restrict__ dst,
                                                  int* __restrict__ histc) {
    __shared__ __align__(16) float sc[4 * NBKT];  // union: gemv consts (516) / hist (784)
    int t = threadIdx.x;
    if (blockIdx.x >= GEMV_BLKS) {
        // ---- histogram role: per-wave private counters ----
        int* lh = (int*)sc;
        int k = blockIdx.x - GEMV_BLKS;
        for (int i = t; i < 4 * NBKT; i += 256) lh[i] = 0;
        __syncthreads();
        int* mylh = lh + (t >> 6) * NBKT;
        int e0 = k * EPB;
        for (int e = e0 + t; e < e0 + EPB; e += 256)
            atomicAdd(&mylh[dst[e] >> 9], 1);
        __syncthreads();
        for (int i = t; i < NBKT; i += 256)
            histc[i * NCOL + k] = lh[i] + lh[NBKT + i] + lh[2 * NBKT + i] + lh[3 * NBKT + i];
        return;
    }
    // ---- gemv role: 16 lanes per node ----
    for (int i = t; i < 514; i += 256) sc[i] = cvec[i];
    __syncthreads();
    int g = t >> 4, l = t & 15;
    int n = blockIdx.x * 16 + g;
    const float* x = (n < N_USERS) ? (ue + (size_t)n * HID)
                                   : (ie + (size_t)(n - N_USERS) * HID);
    float4 xa = ((const float4*)x)[2 * l];
    float4 xb = ((const float4*)x)[2 * l + 1];
    const float4* u_l = (const float4*)&sc[0];
    const float4* v_l = (const float4*)&sc[128];
    const float4* u_r = (const float4*)&sc[256];
    const float4* v_r = (const float4*)&sc[384];
    float4 w0, w1;
    w0 = u_l[2 * l]; w1 = u_l[2 * l + 1];
    float pl = xa.x * w0.x + xa.y * w0.y + xa.z * w0.z + xa.w * w0.w
             + xb.x * w1.x + xb.y * w1.y + xb.z * w1.z + xb.w * w1.w;
    w0 = v_l[2 * l]; w1 = v_l[2 * l + 1];
    float ql = xa.x * w0.x + xa.y * w0.y + xa.z * w0.z + xa.w * w0.w
             + xb.x * w1.x + xb.y * w1.y + xb.z * w1.z + xb.w * w1.w;
    w0 = u_r[2 * l]; w1 = u_r[2 * l + 1];
    float pr = xa.x * w0.x + xa.y * w0.y + xa.z * w0.z + xa.w * w0.w
             + xb.x * w1.x + xb.y * w1.y + xb.z * w1.z + xb.w * w1.w;
    w0 = v_r[2 * l]; w1 = v_r[2 * l + 1];
    float qr = xa.x * w0.x + xa.y * w0.y + xa.z * w0.z + xa.w * w0.w
             + xb.x * w1.x + xb.y * w1.y + xb.z * w1.z + xb.w * w1.w;
#pragma unroll
    for (int m = 1; m < 16; m <<= 1) {
        pl += __shfl_xor(pl, m);
        ql += __shfl_xor(ql, m);
        pr += __shfl_xor(pr, m);
        qr += __shfl_xor(qr, m);
    }
    if (l == 0) {
        pq[n] = make_float2(pl, pr);
        qq[n] = make_float2(ql + sc[512], qr + sc[513]);
    }
}

// ---------------- scan pass 1: block-local scan over NH, emit partials ----------------
__global__ void k_scanA(const int* __restrict__ in, int* __restrict__ out,
                        int* __restrict__ partials) {
    __shared__ int s[256];
    int t = threadIdx.x;
    int i = blockIdx.x * 256 + t;
    int v = in[i];
    s[t] = v;
    __syncthreads();
    for (int off = 1; off < 256; off <<= 1) {
        int add = (t >= off) ? s[t - off] : 0;
        __syncthreads();
        s[t] += add;
        __syncthreads();
    }
    out[i] = s[t] - v;
    if (t == 255) partials[blockIdx.x] = s[255];
}

// ---------------- scan pass 2: each block derives its own offset from partials ----------------
__global__ void k_scanB(int* __restrict__ out, const int* __restrict__ partials) {
    __shared__ int s[256];
    int t = threadIdx.x, b = blockIdx.x;
    int v = (t < SCAN_H) ? partials[t] : 0;
    s[t] = v;
    __syncthreads();
    for (int off = 1; off < 256; off <<= 1) {
        int add = (t >= off) ? s[t - off] : 0;
        __syncthreads();
        s[t] += add;
        __syncthreads();
    }
    int off = s[b] - partials[b];  // exclusive prefix at b (broadcast read)
    out[b * 256 + t] += off;
}

// ---------------- pass A2: scatter packed (src | dstlocal<<17) into partition ----------------
__global__ __launch_bounds__(512) void k_scatA(const int* __restrict__ src,
                                               const int* __restrict__ dst,
                                               const int* __restrict__ hists,
                                               unsigned* __restrict__ part) {
    __shared__ int cur[NBKT];
    int t = threadIdx.x, k = blockIdx.x;
    for (int i = t; i < NBKT; i += 512) cur[i] = hists[i * NCOL + k];
    __syncthreads();
    int e0 = k * EPB;
    for (int e = e0 + t; e < e0 + EPB; e += 512) {
        int s = src[e], d = dst[e];
        int pos = atomicAdd(&cur[d >> 9], 1);
        part[pos] = (unsigned)s | (((unsigned)d & 511u) << 17);
    }
}

// ---------------- round 1: z_l, z_r, invd (per-wave private accumulators) ----------------
__global__ __launch_bounds__(512) void k_aggs1(const unsigned* __restrict__ part,
                                               const int* __restrict__ hists,
                                               const float2* __restrict__ pq,
                                               const float2* __restrict__ qq,
                                               float* __restrict__ zl,
                                               float* __restrict__ zr,
                                               float* __restrict__ invd) {
    __shared__ float suml[8 * BKTW];  // 16 KB
    __shared__ float sumr[8 * BKTW];  // 16 KB
    __shared__ int   cnt[8 * BKTW];   // 16 KB
    int t = threadIdx.x, b = blockIdx.x;
    int w = t >> 6;
#pragma unroll
    for (int i = 0; i < 8; ++i) {
        suml[t + i * 512] = 0.f;
        sumr[t + i * 512] = 0.f;
        cnt[t + i * 512] = 0;
    }
    __syncthreads();
    float* msl = suml + w * BKTW;
    float* msr = sumr + w * BKTW;
    int*   mc  = cnt + w * BKTW;
    int p0 = hists[b * NCOL];
    int p1 = (b + 1 < NBKT) ? hists[(b + 1) * NCOL] : N_EDGES;
    for (int e = p0 + t; e < p1; e += 512) {
        unsigned enc = part[e];
        float2 p = pq[enc & 0x1FFFFu];
        int dl = enc >> 17;
        atomicAdd(&msl[dl], p.x);
        atomicAdd(&msr[dl], p.y);
        atomicAdd(&mc[dl], 1);
    }
    __syncthreads();
    float sl = 0.f, sr = 0.f;
    int c = 0;
#pragma unroll
    for (int i = 0; i < 8; ++i) {
        sl += suml[i * BKTW + t];
        sr += sumr[i * BKTW + t];
        c += cnt[i * BKTW + t];
    }
    int n = b * BKTW + t;
    if (n < N_NODES) {
        float wi = 1.f / (float)max(c, 1);
        float2 q = qq[n];
        zl[n] = sl * wi + q.x;
        zr[n] = sr * wi + q.y;
        invd[n] = wi;
    }
}

// ---------------- round 2: y = invd * sum_nbr(z_l) + z_r ----------------
__global__ __launch_bounds__(512) void k_aggs2(const unsigned* __restrict__ part,
                                               const int* __restrict__ hists,
                                               const float* __restrict__ zl,
                                               const float* __restrict__ zr,
                                               const float* __restrict__ invd,
                                               float* __restrict__ y) {
    __shared__ float sum[8 * BKTW];  // 16 KB
    int t = threadIdx.x, b = blockIdx.x;
    int w = t >> 6;
#pragma unroll
    for (int i = 0; i < 8; ++i) sum[t + i * 512] = 0.f;
    __syncthreads();
    float* ms = sum + w * BKTW;
    int p0 = hists[b * NCOL];
    int p1 = (b + 1 < NBKT) ? hists[(b + 1) * NCOL] : N_EDGES;
    for (int e = p0 + t; e < p1; e += 512) {
        unsigned enc = part[e];
        atomicAdd(&ms[enc >> 17], zl[enc & 0x1FFFFu]);
    }
    __syncthreads();
    float s = 0.f;
#pragma unroll
    for (int i = 0; i < 8; ++i) s += sum[i * BKTW + t];
    int n = b * BKTW + t;
    if (n < N_NODES) y[n] = s * invd[n] + zr[n];
}

// ---------------- softmax over gathered items (no max pass: |y| ~ 1e-3) ----------------
__global__ void k_sumexp(const float* __restrict__ y, const int* __restrict__ item,
                         float* __restrict__ redsum) {
    float s = 0.f;
    for (int i = blockIdx.x * blockDim.x + threadIdx.x; i < N_ITEMS; i += gridDim.x * blockDim.x)
        s += expf(y[item[i]]);
#pragma unroll
    for (int off = 32; off; off >>= 1) s += __shfl_down(s, off, 64);
    __shared__ float sm[4];
    int lane = threadIdx.x & 63, wave = threadIdx.x >> 6;
    if (lane == 0) sm[wave] = s;
    __syncthreads();
    if (threadIdx.x == 0) atomicAdd(redsum, sm[0] + sm[1] + sm[2] + sm[3]);
}

__global__ void k_out(const float* __restrict__ y, const int* __restrict__ item,
                      const float* __restrict__ redsum, const float* __restrict__ dprior,
                      float* __restrict__ out) {
    float inv_s = 1.0f / (*redsum);
    float pr = fmaxf(dprior[0], 0.f);
    for (int i = blockIdx.x * blockDim.x + threadIdx.x; i < N_ITEMS; i += gridDim.x * blockDim.x)
        out[i] = pr * expf(y[item[i]]) * inv_s;
}

extern "C" void kernel_launch(void* const* d_in, const int* in_sizes, int n_in,
                              void* d_out, int out_size, void* d_ws, size_t ws_size,
                              hipStream_t stream) {
    const int*   item  = (const int*)d_in[0];
    const int*   esrc  = (const int*)d_in[1];
    const int*   edst  = esrc + N_EDGES;
    const float* ue    = (const float*)d_in[2];
    const float* ie    = (const float*)d_in[3];
    const float* Wl1   = (const float*)d_in[4];
    const float* Wr1   = (const float*)d_in[5];
    const float* b1    = (const float*)d_in[6];
    const float* Wl2   = (const float*)d_in[7];
    const float* Wr2   = (const float*)d_in[8];
    const float* b2    = (const float*)d_in[9];
    const float* Wout  = (const float*)d_in[10];
    const float* bout  = (const float*)d_in[11];
    const float* dpri  = (const float*)d_in[12];
    float* out = (float*)d_out;

    // workspace (~12 MB)
    unsigned* part = (unsigned*)d_ws;                 // N_EDGES packed (6.4 MB)
    float2*   pq   = (float2*)(part + N_EDGES);       // N_NODES (p_l, p_r)
    float2*   qq   = pq + N_NODES;                    // N_NODES (q_l+c_l, q_r+c_r+c)
    float*    zl   = (float*)(qq + N_NODES);          // N_NODES
    float*    zr   = zl + N_NODES;                    // N_NODES
    float*    invd = zr + N_NODES;                    // N_NODES
    float*    y    = invd + N_NODES;                  // N_NODES
    int*      histc   = (int*)(y + N_NODES);          // NH
    int*      hists   = histc + NH;                   // NH
    int*      parts_h = hists + NH;                   // 512
    float*    cvec    = (float*)(parts_h + 512);      // 516
    float*    redsum  = cvec + 516;

    // weight collapse (+ redsum zero) ; per-node scalars + edge histogram (fused)
    k_prep<<<1, 256, 0, stream>>>(Wl1, Wr1, b1, Wl2, Wr2, b2, Wout, bout, cvec, redsum);
    k_gemvhist<<<GEMV_BLKS + NCOL, 256, 0, stream>>>(ue, ie, cvec, pq, qq, edst, histc);

    // partition-offset scan (2 kernels)
    k_scanA<<<SCAN_H, 256, 0, stream>>>(histc, hists, parts_h);
    k_scanB<<<SCAN_H, 256, 0, stream>>>(hists, parts_h);

    // bucket-partition the edge list
    k_scatA<<<NCOL, 512, 0, stream>>>(esrc, edst, hists, part);

    // two scalar aggregation rounds
    k_aggs1<<<NBKT, 512, 0, stream>>>(part, hists, pq, qq, zl, zr, invd);
    k_aggs2<<<NBKT, 512, 0, stream>>>(part, hists, zl, zr, invd, y);

    // softmax over gathered items
    k_sumexp<<<200, 256, 0, stream>>>(y, item, redsum);
    k_out<<<200, 256, 0, stream>>>(y, item, redsum, dpri, out);
}